// Round 5
// baseline (32.610 us; speedup 1.0000x reference)
//
#include <hip/hip_runtime.h>

#define MARGIN 0.2f
#define EPS 1e-8f
#define GRID_BLOCKS 2048

typedef _Float16 h2 __attribute__((ext_vector_type(2)));
typedef _Float16 h8 __attribute__((ext_vector_type(8)));
union H8 { h8 v; h2 p[4]; };

// ---- prep: fp32->fp16 convert + per-triplet {aoff,poff,noff,beta} ---------

__global__ __launch_bounds__(256) void prep_kernel(
    const float* __restrict__ batch,
    const int* __restrict__ labels,
    const int* __restrict__ triplets,
    const float* __restrict__ beta,
    _Float16* __restrict__ batch16,
    int4* __restrict__ prep,
    int n4, int T)
{
    int i = blockIdx.x * blockDim.x + threadIdx.x;
    if (i < n4) {
        float4 f = *(const float4*)(batch + 4 * (size_t)i);
        h2 lo, hi;
        lo.x = (_Float16)f.x; lo.y = (_Float16)f.y;
        hi.x = (_Float16)f.z; hi.y = (_Float16)f.w;
        *(h2*)(batch16 + 4 * (size_t)i)     = lo;
        *(h2*)(batch16 + 4 * (size_t)i + 2) = hi;
    }
    if (i < T) {
        int a = triplets[3 * i + 0];
        int p = triplets[3 * i + 1];
        int n = triplets[3 * i + 2];
        float b = beta[labels[a]];
        int4 s;
        s.x = a << 7;               // element offset of row (128 fp16/row)
        s.y = p << 7;
        s.z = n << 7;
        s.w = __float_as_int(b);
        prep[i] = s;
    }
}

// ---- main: 8 lanes per triplet, full-cache-line gathers, unroll x2 --------
// Row = 128 fp16 = 256B = 16 h8 chunks. Lane fi (0..7) loads chunks fi and
// fi+8: each wave VMEM instruction covers one full 128B line per 8-lane
// group (8 lines / 1KB per instruction) -- minimal L1 transactions.
// All 12 row loads of both unrolled triplets issue before any compute.
// After the 3-step butterfly all 8 lanes hold the sums; every lane computes
// the hinge (8x duplicated, scaled out in finalize) -- no exec-mask churn.
__global__ __launch_bounds__(256) void triplet_main_kernel(
    const _Float16* __restrict__ batch16,
    const int4* __restrict__ prep,
    float* __restrict__ partial,   // [gridDim.x * 2], 8x-scaled
    int T)
{
    const int lane = threadIdx.x & 63;
    const int wid  = threadIdx.x >> 6;   // wave 0..3
    const int sub  = lane >> 3;          // triplet slot 0..7
    const int fi   = lane & 7;           // h8 chunk 0..7

    float loss = 0.f, cnt = 0.f;
    const int Tm1 = T - 1;

    for (int base = blockIdx.x * 64; base < T; base += gridDim.x * 64) {
        int tA = base + wid * 16 + sub;
        int tB = tA + 8;
        int cA = tA > Tm1 ? Tm1 : tA;
        int cB = tB > Tm1 ? Tm1 : tB;
        int4 sA = prep[cA];
        int4 sB = prep[cB];

        const h8* __restrict__ arA = (const h8*)(batch16 + (size_t)(unsigned)sA.x);
        const h8* __restrict__ prA = (const h8*)(batch16 + (size_t)(unsigned)sA.y);
        const h8* __restrict__ nrA = (const h8*)(batch16 + (size_t)(unsigned)sA.z);
        const h8* __restrict__ arB = (const h8*)(batch16 + (size_t)(unsigned)sB.x);
        const h8* __restrict__ prB = (const h8*)(batch16 + (size_t)(unsigned)sB.y);
        const h8* __restrict__ nrB = (const h8*)(batch16 + (size_t)(unsigned)sB.z);

        H8 a0A, a1A, p0A, p1A, n0A, n1A;
        H8 a0B, a1B, p0B, p1B, n0B, n1B;
        a0A.v = arA[fi]; a1A.v = arA[fi + 8];
        p0A.v = prA[fi]; p1A.v = prA[fi + 8];
        n0A.v = nrA[fi]; n1A.v = nrA[fi + 8];
        a0B.v = arB[fi]; a1B.v = arB[fi + 8];
        p0B.v = prB[fi]; p1B.v = prB[fi + 8];
        n0B.v = nrB[fi]; n1B.v = nrB[fi + 8];

        float sapA = 0.f, sanA = 0.f, sapB = 0.f, sanB = 0.f;
        {
            H8 d;
            d.v = a0A.v - p0A.v;
            #pragma unroll
            for (int j = 0; j < 4; ++j) sapA = __builtin_amdgcn_fdot2(d.p[j], d.p[j], sapA, false);
            d.v = a1A.v - p1A.v;
            #pragma unroll
            for (int j = 0; j < 4; ++j) sapA = __builtin_amdgcn_fdot2(d.p[j], d.p[j], sapA, false);
            d.v = a0A.v - n0A.v;
            #pragma unroll
            for (int j = 0; j < 4; ++j) sanA = __builtin_amdgcn_fdot2(d.p[j], d.p[j], sanA, false);
            d.v = a1A.v - n1A.v;
            #pragma unroll
            for (int j = 0; j < 4; ++j) sanA = __builtin_amdgcn_fdot2(d.p[j], d.p[j], sanA, false);
            d.v = a0B.v - p0B.v;
            #pragma unroll
            for (int j = 0; j < 4; ++j) sapB = __builtin_amdgcn_fdot2(d.p[j], d.p[j], sapB, false);
            d.v = a1B.v - p1B.v;
            #pragma unroll
            for (int j = 0; j < 4; ++j) sapB = __builtin_amdgcn_fdot2(d.p[j], d.p[j], sapB, false);
            d.v = a0B.v - n0B.v;
            #pragma unroll
            for (int j = 0; j < 4; ++j) sanB = __builtin_amdgcn_fdot2(d.p[j], d.p[j], sanB, false);
            d.v = a1B.v - n1B.v;
            #pragma unroll
            for (int j = 0; j < 4; ++j) sanB = __builtin_amdgcn_fdot2(d.p[j], d.p[j], sanB, false);
        }

        // butterfly across the 8-lane group
        #pragma unroll
        for (int off = 4; off >= 1; off >>= 1) {
            sapA += __shfl_xor(sapA, off);
            sanA += __shfl_xor(sanA, off);
            sapB += __shfl_xor(sapB, off);
            sanB += __shfl_xor(sanB, off);
        }

        float bA = __int_as_float(sA.w);
        float bB = __int_as_float(sB.w);
        float mA = (tA < T) ? 1.f : 0.f;
        float mB = (tB < T) ? 1.f : 0.f;

        float dapA = sqrtf(sapA + EPS), danA = sqrtf(sanA + EPS);
        float posA = fmaxf(dapA - bA + MARGIN, 0.f);
        float negA = fmaxf(bA - danA + MARGIN, 0.f);
        loss += mA * (posA + negA);
        cnt  += mA * ((posA > 0.f ? 1.f : 0.f) + (negA > 0.f ? 1.f : 0.f));

        float dapB = sqrtf(sapB + EPS), danB = sqrtf(sanB + EPS);
        float posB = fmaxf(dapB - bB + MARGIN, 0.f);
        float negB = fmaxf(bB - danB + MARGIN, 0.f);
        loss += mB * (posB + negB);
        cnt  += mB * ((posB > 0.f ? 1.f : 0.f) + (negB > 0.f ? 1.f : 0.f));
    }

    #pragma unroll
    for (int off = 32; off >= 1; off >>= 1) {
        loss += __shfl_down(loss, off);
        cnt  += __shfl_down(cnt, off);
    }
    __shared__ float sl[4], sc[4];
    if (lane == 0) { sl[wid] = loss; sc[wid] = cnt; }
    __syncthreads();
    if (threadIdx.x == 0) {
        partial[blockIdx.x * 2 + 0] = sl[0] + sl[1] + sl[2] + sl[3];
        partial[blockIdx.x * 2 + 1] = sc[0] + sc[1] + sc[2] + sc[3];
    }
}

// ---- fp32 fallback (round-3 kernel, known-good) ---------------------------

__global__ __launch_bounds__(256) void triplet_loss_f32_kernel(
    const float* __restrict__ batch,
    const int* __restrict__ labels,
    const int* __restrict__ triplets,
    const float* __restrict__ beta,
    float* __restrict__ partial,
    int T)
{
    const int lane = threadIdx.x & 63;
    const int wid  = threadIdx.x >> 6;
    const int sub  = lane >> 3;
    const int fi   = lane & 7;

    float loss = 0.f, cnt = 0.f;

    for (int base = blockIdx.x * 32; base < T; base += gridDim.x * 32) {
        int t = base + wid * 8 + sub;
        if (t < T) {
            int ai = triplets[3 * t + 0];
            int pi = triplets[3 * t + 1];
            int ni = triplets[3 * t + 2];
            float b = beta[labels[ai]];
            const float4* __restrict__ arow = (const float4*)(batch + ((size_t)ai << 7));
            const float4* __restrict__ prow = (const float4*)(batch + ((size_t)pi << 7));
            const float4* __restrict__ nrow = (const float4*)(batch + ((size_t)ni << 7));
            float sap = 0.f, san = 0.f;
            #pragma unroll
            for (int k = 0; k < 4; ++k) {
                float4 av = arow[fi + 8 * k];
                float4 pv = prow[fi + 8 * k];
                float4 nv = nrow[fi + 8 * k];
                float d;
                d = av.x - pv.x; sap += d * d;
                d = av.y - pv.y; sap += d * d;
                d = av.z - pv.z; sap += d * d;
                d = av.w - pv.w; sap += d * d;
                d = av.x - nv.x; san += d * d;
                d = av.y - nv.y; san += d * d;
                d = av.z - nv.z; san += d * d;
                d = av.w - nv.w; san += d * d;
            }
            #pragma unroll
            for (int off = 4; off >= 1; off >>= 1) {
                sap += __shfl_xor(sap, off);
                san += __shfl_xor(san, off);
            }
            float d_ap = sqrtf(sap + EPS);
            float d_an = sqrtf(san + EPS);
            float pos = fmaxf(d_ap - b + MARGIN, 0.f);
            float neg = fmaxf(b - d_an + MARGIN, 0.f);
            loss += pos + neg;
            cnt  += (pos > 0.f ? 1.f : 0.f) + (neg > 0.f ? 1.f : 0.f);
        }
    }

    #pragma unroll
    for (int off = 32; off >= 1; off >>= 1) {
        loss += __shfl_down(loss, off);
        cnt  += __shfl_down(cnt, off);
    }
    __shared__ float sl[4], sc[4];
    if (lane == 0) { sl[wid] = loss; sc[wid] = cnt; }
    __syncthreads();
    if (threadIdx.x == 0) {
        partial[blockIdx.x * 2 + 0] = sl[0] + sl[1] + sl[2] + sl[3];
        partial[blockIdx.x * 2 + 1] = sc[0] + sc[1] + sc[2] + sc[3];
    }
}

// ---- finalize --------------------------------------------------------------

__global__ __launch_bounds__(1024) void triplet_finalize_kernel(
    const float* __restrict__ partial, float* __restrict__ out, int nblocks,
    float scale)
{
    float L = 0.f, C = 0.f;
    for (int i = threadIdx.x; i < nblocks; i += blockDim.x) {
        L += partial[2 * i + 0];
        C += partial[2 * i + 1];
    }
    #pragma unroll
    for (int off = 32; off >= 1; off >>= 1) {
        L += __shfl_down(L, off);
        C += __shfl_down(C, off);
    }
    __shared__ float sl[16], sc[16];
    int wid  = threadIdx.x >> 6;
    int lane = threadIdx.x & 63;
    int nw   = blockDim.x >> 6;
    if (lane == 0) { sl[wid] = L; sc[wid] = C; }
    __syncthreads();
    if (threadIdx.x == 0) {
        float Lt = 0.f, Ct = 0.f;
        for (int i = 0; i < nw; ++i) { Lt += sl[i]; Ct += sc[i]; }
        Lt *= scale;
        Ct *= scale;
        out[0] = (Ct > 0.f) ? (Lt / fmaxf(Ct, 1.f)) : Lt;
    }
}

extern "C" void kernel_launch(void* const* d_in, const int* in_sizes, int n_in,
                              void* d_out, int out_size, void* d_ws, size_t ws_size,
                              hipStream_t stream) {
    const float* batch    = (const float*)d_in[0];
    const int*   labels   = (const int*)d_in[1];
    const int*   triplets = (const int*)d_in[2];
    const float* beta     = (const float*)d_in[3];
    float* out = (float*)d_out;

    int nbatch = in_sizes[0];          // 4096*128
    int T = in_sizes[2] / 3;

    size_t f16_bytes  = ((size_t)nbatch * sizeof(_Float16) + 255) & ~(size_t)255;
    size_t prep_bytes = ((size_t)T * sizeof(int4) + 255) & ~(size_t)255;
    size_t need = f16_bytes + prep_bytes + (size_t)GRID_BLOCKS * 2 * sizeof(float);

    if (ws_size >= need) {
        _Float16* batch16 = (_Float16*)d_ws;
        int4* prep        = (int4*)((char*)d_ws + f16_bytes);
        float* partial    = (float*)((char*)d_ws + f16_bytes + prep_bytes);

        int n4 = nbatch / 4;
        int prep_items = (T > n4) ? T : n4;
        prep_kernel<<<(prep_items + 255) / 256, 256, 0, stream>>>(
            batch, labels, triplets, beta, batch16, prep, n4, T);

        int grid = GRID_BLOCKS;
        int groups = (T + 63) / 64;
        if (grid > groups) grid = groups;
        triplet_main_kernel<<<grid, 256, 0, stream>>>(batch16, prep, partial, T);
        triplet_finalize_kernel<<<1, 1024, 0, stream>>>(partial, out, grid, 0.125f);
    } else {
        float* partial = (float*)d_ws;
        int grid = GRID_BLOCKS;
        int groups = (T + 31) / 32;
        if (grid > groups) grid = groups;
        triplet_loss_f32_kernel<<<grid, 256, 0, stream>>>(batch, labels, triplets, beta, partial, T);
        triplet_finalize_kernel<<<1, 1024, 0, stream>>>(partial, out, grid, 0.125f);
    }
}

// Round 7
// 31.669 us; speedup vs baseline: 1.0297x; 1.0297x over previous
//
#include <hip/hip_runtime.h>

#define MARGIN 0.2f
#define EPS 1e-8f
#define GRID_BLOCKS 2048

typedef float f32x2 __attribute__((ext_vector_type(2)));

// ---- prep: fp32->fp8(e4m3) convert + per-triplet {aoff,poff,noff,beta} ----

__global__ __launch_bounds__(256) void prep_kernel(
    const float* __restrict__ batch,
    const int* __restrict__ labels,
    const int* __restrict__ triplets,
    const float* __restrict__ beta,
    unsigned char* __restrict__ batch8,
    int4* __restrict__ prep,
    int n8, int T)
{
    int i = blockIdx.x * blockDim.x + threadIdx.x;
    if (i < n8) {
        const float4* src = (const float4*)(batch + (size_t)i * 8);
        float4 f0 = src[0];
        float4 f1 = src[1];
        int lo = __builtin_amdgcn_cvt_pk_fp8_f32(f0.x, f0.y, 0, false);
        lo     = __builtin_amdgcn_cvt_pk_fp8_f32(f0.z, f0.w, lo, true);
        int hi = __builtin_amdgcn_cvt_pk_fp8_f32(f1.x, f1.y, 0, false);
        hi     = __builtin_amdgcn_cvt_pk_fp8_f32(f1.z, f1.w, hi, true);
        uint2 w;
        w.x = (unsigned)lo;
        w.y = (unsigned)hi;
        *(uint2*)(batch8 + (size_t)i * 8) = w;
    }
    if (i < T) {
        int a = triplets[3 * i + 0];
        int p = triplets[3 * i + 1];
        int n = triplets[3 * i + 2];
        float b = beta[labels[a]];
        int4 s;
        s.x = a << 7;               // byte offset of row (128 B/row in fp8)
        s.y = p << 7;
        s.z = n << 7;
        s.w = __float_as_int(b);
        prep[i] = s;
    }
}

// ---- main: fp8 rows, 8 lanes/triplet, unroll x2 ---------------------------
// Row = 128 fp8 = 128B. Lane fi (0..7) loads uint4 (16B) at byte fi*16:
// one load instruction per row per 8-lane group covers the WHOLE row ->
// 2 x 64B L2 requests per row, 6 per triplet (half of the fp16 path).
// Decode 2 fp8->f32 per v_cvt_pk_f32_fp8; accumulate in f32 fma.
// After the 3-step butterfly all 8 lanes hold the sums; every lane computes
// the hinge (8x duplicated, scaled out in finalize).
__global__ __launch_bounds__(256) void triplet_main_kernel(
    const unsigned char* __restrict__ batch8,
    const int4* __restrict__ prep,
    float* __restrict__ partial,   // [gridDim.x * 2], 8x-scaled
    int T)
{
    const int lane = threadIdx.x & 63;
    const int wid  = threadIdx.x >> 6;   // wave 0..3
    const int sub  = lane >> 3;          // triplet slot 0..7
    const int fi   = lane & 7;           // 16B chunk 0..7 within row

    float loss = 0.f, cnt = 0.f;
    const int Tm1 = T - 1;

    auto accum = [&](const uint4& A, const uint4& P, const uint4& N,
                     float& sap, float& san) {
        #pragma unroll
        for (int w = 0; w < 4; ++w) {
            unsigned aw = (&A.x)[w];
            unsigned pw = (&P.x)[w];
            unsigned nw = (&N.x)[w];
            f32x2 a0 = __builtin_amdgcn_cvt_pk_f32_fp8(aw, false);
            f32x2 a1 = __builtin_amdgcn_cvt_pk_f32_fp8(aw, true);
            f32x2 p0 = __builtin_amdgcn_cvt_pk_f32_fp8(pw, false);
            f32x2 p1 = __builtin_amdgcn_cvt_pk_f32_fp8(pw, true);
            f32x2 n0 = __builtin_amdgcn_cvt_pk_f32_fp8(nw, false);
            f32x2 n1 = __builtin_amdgcn_cvt_pk_f32_fp8(nw, true);
            float d;
            d = a0[0] - p0[0]; sap = fmaf(d, d, sap);
            d = a0[1] - p0[1]; sap = fmaf(d, d, sap);
            d = a1[0] - p1[0]; sap = fmaf(d, d, sap);
            d = a1[1] - p1[1]; sap = fmaf(d, d, sap);
            d = a0[0] - n0[0]; san = fmaf(d, d, san);
            d = a0[1] - n0[1]; san = fmaf(d, d, san);
            d = a1[0] - n1[0]; san = fmaf(d, d, san);
            d = a1[1] - n1[1]; san = fmaf(d, d, san);
        }
    };

    for (int base = blockIdx.x * 64; base < T; base += gridDim.x * 64) {
        int tA = base + wid * 16 + sub;
        int tB = tA + 8;
        int cA = tA > Tm1 ? Tm1 : tA;
        int cB = tB > Tm1 ? Tm1 : tB;
        int4 sA = prep[cA];
        int4 sB = prep[cB];

        int boff = fi << 4;
        uint4 AA = *(const uint4*)(batch8 + (size_t)(unsigned)sA.x + boff);
        uint4 PA = *(const uint4*)(batch8 + (size_t)(unsigned)sA.y + boff);
        uint4 NA = *(const uint4*)(batch8 + (size_t)(unsigned)sA.z + boff);
        uint4 AB = *(const uint4*)(batch8 + (size_t)(unsigned)sB.x + boff);
        uint4 PB = *(const uint4*)(batch8 + (size_t)(unsigned)sB.y + boff);
        uint4 NB = *(const uint4*)(batch8 + (size_t)(unsigned)sB.z + boff);

        float sapA = 0.f, sanA = 0.f, sapB = 0.f, sanB = 0.f;
        accum(AA, PA, NA, sapA, sanA);
        accum(AB, PB, NB, sapB, sanB);

        // butterfly across the 8-lane group
        #pragma unroll
        for (int off = 4; off >= 1; off >>= 1) {
            sapA += __shfl_xor(sapA, off);
            sanA += __shfl_xor(sanA, off);
            sapB += __shfl_xor(sapB, off);
            sanB += __shfl_xor(sanB, off);
        }

        float bA = __int_as_float(sA.w);
        float bB = __int_as_float(sB.w);
        float mA = (tA < T) ? 1.f : 0.f;
        float mB = (tB < T) ? 1.f : 0.f;

        float dapA = sqrtf(sapA + EPS), danA = sqrtf(sanA + EPS);
        float posA = fmaxf(dapA - bA + MARGIN, 0.f);
        float negA = fmaxf(bA - danA + MARGIN, 0.f);
        loss += mA * (posA + negA);
        cnt  += mA * ((posA > 0.f ? 1.f : 0.f) + (negA > 0.f ? 1.f : 0.f));

        float dapB = sqrtf(sapB + EPS), danB = sqrtf(sanB + EPS);
        float posB = fmaxf(dapB - bB + MARGIN, 0.f);
        float negB = fmaxf(bB - danB + MARGIN, 0.f);
        loss += mB * (posB + negB);
        cnt  += mB * ((posB > 0.f ? 1.f : 0.f) + (negB > 0.f ? 1.f : 0.f));
    }

    #pragma unroll
    for (int off = 32; off >= 1; off >>= 1) {
        loss += __shfl_down(loss, off);
        cnt  += __shfl_down(cnt, off);
    }
    __shared__ float sl[4], sc[4];
    if (lane == 0) { sl[wid] = loss; sc[wid] = cnt; }
    __syncthreads();
    if (threadIdx.x == 0) {
        partial[blockIdx.x * 2 + 0] = sl[0] + sl[1] + sl[2] + sl[3];
        partial[blockIdx.x * 2 + 1] = sc[0] + sc[1] + sc[2] + sc[3];
    }
}

// ---- fp32 fallback (round-3 kernel, known-good) ---------------------------

__global__ __launch_bounds__(256) void triplet_loss_f32_kernel(
    const float* __restrict__ batch,
    const int* __restrict__ labels,
    const int* __restrict__ triplets,
    const float* __restrict__ beta,
    float* __restrict__ partial,
    int T)
{
    const int lane = threadIdx.x & 63;
    const int wid  = threadIdx.x >> 6;
    const int sub  = lane >> 3;
    const int fi   = lane & 7;

    float loss = 0.f, cnt = 0.f;

    for (int base = blockIdx.x * 32; base < T; base += gridDim.x * 32) {
        int t = base + wid * 8 + sub;
        if (t < T) {
            int ai = triplets[3 * t + 0];
            int pi = triplets[3 * t + 1];
            int ni = triplets[3 * t + 2];
            float b = beta[labels[ai]];
            const float4* __restrict__ arow = (const float4*)(batch + ((size_t)ai << 7));
            const float4* __restrict__ prow = (const float4*)(batch + ((size_t)pi << 7));
            const float4* __restrict__ nrow = (const float4*)(batch + ((size_t)ni << 7));
            float sap = 0.f, san = 0.f;
            #pragma unroll
            for (int k = 0; k < 4; ++k) {
                float4 av = arow[fi + 8 * k];
                float4 pv = prow[fi + 8 * k];
                float4 nv = nrow[fi + 8 * k];
                float d;
                d = av.x - pv.x; sap += d * d;
                d = av.y - pv.y; sap += d * d;
                d = av.z - pv.z; sap += d * d;
                d = av.w - pv.w; sap += d * d;
                d = av.x - nv.x; san += d * d;
                d = av.y - nv.y; san += d * d;
                d = av.z - nv.z; san += d * d;
                d = av.w - nv.w; san += d * d;
            }
            #pragma unroll
            for (int off = 4; off >= 1; off >>= 1) {
                sap += __shfl_xor(sap, off);
                san += __shfl_xor(san, off);
            }
            float d_ap = sqrtf(sap + EPS);
            float d_an = sqrtf(san + EPS);
            float pos = fmaxf(d_ap - b + MARGIN, 0.f);
            float neg = fmaxf(b - d_an + MARGIN, 0.f);
            loss += pos + neg;
            cnt  += (pos > 0.f ? 1.f : 0.f) + (neg > 0.f ? 1.f : 0.f);
        }
    }

    #pragma unroll
    for (int off = 32; off >= 1; off >>= 1) {
        loss += __shfl_down(loss, off);
        cnt  += __shfl_down(cnt, off);
    }
    __shared__ float sl[4], sc[4];
    if (lane == 0) { sl[wid] = loss; sc[wid] = cnt; }
    __syncthreads();
    if (threadIdx.x == 0) {
        partial[blockIdx.x * 2 + 0] = sl[0] + sl[1] + sl[2] + sl[3];
        partial[blockIdx.x * 2 + 1] = sc[0] + sc[1] + sc[2] + sc[3];
    }
}

// ---- finalize --------------------------------------------------------------

__global__ __launch_bounds__(1024) void triplet_finalize_kernel(
    const float* __restrict__ partial, float* __restrict__ out, int nblocks,
    float scale)
{
    float L = 0.f, C = 0.f;
    for (int i = threadIdx.x; i < nblocks; i += blockDim.x) {
        L += partial[2 * i + 0];
        C += partial[2 * i + 1];
    }
    #pragma unroll
    for (int off = 32; off >= 1; off >>= 1) {
        L += __shfl_down(L, off);
        C += __shfl_down(C, off);
    }
    __shared__ float sl[16], sc[16];
    int wid  = threadIdx.x >> 6;
    int lane = threadIdx.x & 63;
    int nw   = blockDim.x >> 6;
    if (lane == 0) { sl[wid] = L; sc[wid] = C; }
    __syncthreads();
    if (threadIdx.x == 0) {
        float Lt = 0.f, Ct = 0.f;
        for (int i = 0; i < nw; ++i) { Lt += sl[i]; Ct += sc[i]; }
        Lt *= scale;
        Ct *= scale;
        out[0] = (Ct > 0.f) ? (Lt / fmaxf(Ct, 1.f)) : Lt;
    }
}

extern "C" void kernel_launch(void* const* d_in, const int* in_sizes, int n_in,
                              void* d_out, int out_size, void* d_ws, size_t ws_size,
                              hipStream_t stream) {
    const float* batch    = (const float*)d_in[0];
    const int*   labels   = (const int*)d_in[1];
    const int*   triplets = (const int*)d_in[2];
    const float* beta     = (const float*)d_in[3];
    float* out = (float*)d_out;

    int nbatch = in_sizes[0];          // 4096*128
    int T = in_sizes[2] / 3;

    size_t f8_bytes   = ((size_t)nbatch + 255) & ~(size_t)255;
    size_t prep_bytes = ((size_t)T * sizeof(int4) + 255) & ~(size_t)255;
    size_t need = f8_bytes + prep_bytes + (size_t)GRID_BLOCKS * 2 * sizeof(float);

    if (ws_size >= need) {
        unsigned char* batch8 = (unsigned char*)d_ws;
        int4* prep            = (int4*)((char*)d_ws + f8_bytes);
        float* partial        = (float*)((char*)d_ws + f8_bytes + prep_bytes);

        int n8 = nbatch / 8;
        int prep_items = (T > n8) ? T : n8;
        prep_kernel<<<(prep_items + 255) / 256, 256, 0, stream>>>(
            batch, labels, triplets, beta, batch8, prep, n8, T);

        int grid = GRID_BLOCKS;
        int groups = (T + 63) / 64;
        if (grid > groups) grid = groups;
        triplet_main_kernel<<<grid, 256, 0, stream>>>(batch8, prep, partial, T);
        triplet_finalize_kernel<<<1, 1024, 0, stream>>>(partial, out, grid, 0.125f);
    } else {
        float* partial = (float*)d_ws;
        int grid = GRID_BLOCKS;
        int groups = (T + 31) / 32;
        if (grid > groups) grid = groups;
        triplet_loss_f32_kernel<<<grid, 256, 0, stream>>>(batch, labels, triplets, beta, partial, T);
        triplet_finalize_kernel<<<1, 1024, 0, stream>>>(partial, out, grid, 0.125f);
    }
}